// Round 16
// baseline (402.905 us; speedup 1.0000x reference)
//
#include <hip/hip_runtime.h>
#include <hip/hip_bf16.h>
#include <math.h>

#define S_TOK 8192
#define M_DIM 1024
#define E_NUM 8
#define F_DIM 4096
#define CAP   1024

typedef short short8 __attribute__((ext_vector_type(8)));
typedef float f32x4 __attribute__((ext_vector_type(4)));
typedef unsigned short ushortx4 __attribute__((ext_vector_type(4)));

__device__ inline unsigned short f2bf(float f) {
    union { float f; unsigned int u; } v; v.f = f;
    unsigned int r = v.u + 0x7fffu + ((v.u >> 16) & 1u);
    return (unsigned short)(r >> 16);
}

// gelu(x) = 0.5 x (1 + tanh(y)), y = c(x + 0.044715 x^3) = x*e/(e+1), e=exp(2y)
__device__ inline float gelu_fast(float x) {
    float y = 0.7978845608028654f * (x + 0.044715f * x * x * x);
    if (y > 40.f) return x;
    float e = exp2f(2.8853900817779268f * y);
    return x * e / (e + 1.0f);
}

__device__ inline void gl_lds16(const void* g, void* l) {
    __builtin_amdgcn_global_load_lds(
        (const __attribute__((address_space(1))) unsigned int*)g,
        (__attribute__((address_space(3))) unsigned int*)l, 16, 0, 0);
}

// ---------------- gating ----------------
__global__ __launch_bounds__(256) void gating_kernel(
    const float* __restrict__ x, const float* __restrict__ wg,
    int* __restrict__ idx, float* __restrict__ gate)
{
    int wid = threadIdx.x >> 6;
    int lane = threadIdx.x & 63;
    int s = blockIdx.x * 4 + wid;
    const float* xs = x + (size_t)s * M_DIM;

    double acc[E_NUM];
#pragma unroll
    for (int e = 0; e < E_NUM; e++) acc[e] = 0.0;

    for (int i = lane; i < M_DIM; i += 64) {
        float xv = xs[i];
        float4 wa = *(const float4*)(wg + (size_t)i * E_NUM);
        float4 wb = *(const float4*)(wg + (size_t)i * E_NUM + 4);
        acc[0] += (double)xv * (double)wa.x;
        acc[1] += (double)xv * (double)wa.y;
        acc[2] += (double)xv * (double)wa.z;
        acc[3] += (double)xv * (double)wa.w;
        acc[4] += (double)xv * (double)wb.x;
        acc[5] += (double)xv * (double)wb.y;
        acc[6] += (double)xv * (double)wb.z;
        acc[7] += (double)xv * (double)wb.w;
    }
#pragma unroll
    for (int e = 0; e < E_NUM; e++) {
        double v = acc[e];
        for (int o = 32; o > 0; o >>= 1) v += __shfl_down(v, o, 64);
        acc[e] = v;
    }
    if (lane == 0) {
        double mx = acc[0]; int am = 0;
#pragma unroll
        for (int e = 1; e < E_NUM; e++) {
            if (acc[e] > mx) { mx = acc[e]; am = e; }
        }
        double se = 0.0;
#pragma unroll
        for (int e = 0; e < E_NUM; e++) se += exp(acc[e] - mx);
        idx[s] = am;
        gate[s] = (float)(1.0 / se);
    }
}

// ---------------- scan: token-order slot assignment ----------------
__global__ __launch_bounds__(1024) void scan_build(
    const int* __restrict__ idx, int* __restrict__ srcmap)
{
    __shared__ unsigned int sc[2][4][1024];
    int t = threadIdx.x;

    for (int i = t; i < E_NUM * CAP; i += 1024) srcmap[i] = -1;

    int eid[8];
    unsigned int cnt[E_NUM];
#pragma unroll
    for (int e = 0; e < E_NUM; e++) cnt[e] = 0;
#pragma unroll
    for (int i = 0; i < 8; i++) {
        int e = idx[t * 8 + i];
        eid[i] = e;
        cnt[e]++;
    }
    unsigned int pk[4];
#pragma unroll
    for (int i = 0; i < 4; i++) pk[i] = cnt[2 * i] | (cnt[2 * i + 1] << 16);
#pragma unroll
    for (int i = 0; i < 4; i++) sc[0][i][t] = pk[i];

    int buf = 0;
    for (int ofs = 1; ofs < 1024; ofs <<= 1) {
        __syncthreads();
        unsigned int v[4];
#pragma unroll
        for (int i = 0; i < 4; i++) {
            v[i] = sc[buf][i][t] + ((t >= ofs) ? sc[buf][i][t - ofs] : 0u);
            sc[buf ^ 1][i][t] = v[i];
        }
        buf ^= 1;
    }
    __syncthreads();
    unsigned int pos[E_NUM];
#pragma unroll
    for (int e = 0; e < E_NUM; e++) {
        unsigned int incl = (sc[buf][e >> 1][t] >> ((e & 1) * 16)) & 0xffffu;
        pos[e] = incl - cnt[e];
    }
#pragma unroll
    for (int i = 0; i < 8; i++) {
        int e = eid[i];
        unsigned int p = pos[e]++;
        if (p < CAP) srcmap[e * CAP + p] = t * 8 + i;
    }
}

// ---------------- dispatch: gather rows -> bf16 A1 [E*C][M] ----------------
__global__ __launch_bounds__(256) void dispatch_kernel(
    const float* __restrict__ x, const int* __restrict__ srcmap,
    unsigned short* __restrict__ A1)
{
    int slot = blockIdx.x;
    int s = srcmap[slot];
    int t = threadIdx.x;
    ushortx4 o;
    if (s >= 0) {
        float4 v = ((const float4*)(x + (size_t)s * M_DIM))[t];
        o[0] = f2bf(v.x); o[1] = f2bf(v.y); o[2] = f2bf(v.z); o[3] = f2bf(v.w);
    } else {
        o[0] = 0; o[1] = 0; o[2] = 0; o[3] = 0;
    }
    ((ushortx4*)(A1 + (size_t)slot * M_DIM))[t] = o;
}

// ---------------- transpose + cvt ----------------
__global__ __launch_bounds__(256) void transpose_cvt(
    const float* __restrict__ in, unsigned short* __restrict__ out, int R, int Cc)
{
    __shared__ float tile[32][33];
    int e = blockIdx.z;
    int br = blockIdx.y * 32, bc = blockIdx.x * 32;
    const float* ine = in + (size_t)e * R * Cc;
    unsigned short* oute = out + (size_t)e * R * Cc;
    int tx = threadIdx.x, ty = threadIdx.y;
#pragma unroll
    for (int i = 0; i < 32; i += 8)
        tile[ty + i][tx] = ine[(size_t)(br + ty + i) * Cc + (bc + tx)];
    __syncthreads();
#pragma unroll
    for (int i = 0; i < 32; i += 8)
        oute[(size_t)(bc + ty + i) * R + (br + tx)] = f2bf(tile[tx][ty + i]);
}

// ---------------- 256x256 BK=32 3-slot ring, 8 waves, reg-clean ----------------
// 8 waves (2M x 4N; per-wave 128x64 = acc[8][4] = 128 VGPR). launch_bounds(512,2)
// -> 256 VGPR cap: NO spill (r12's 256^2 attempt was spill-confounded at cap 64).
// 96 KiB LDS ring (3 slots), counted vmcnt(4): one full tile (4 loads/wave) in
// flight across every barrier. Staged bytes: 512 MB per GEMM (minimal geometry).
// r14-verified 0-conflict involution swizzle (64B rows, slot=((row>>1)^q)&3).
// MODE 0 (GEMM1): K=1024, NB=4096: OutH = bf16(gelu(acc+bias)), 2-half repack.
// MODE 1 (GEMM2): split-K=2, NB=1024: OutP[ks] = acc (f32 partials).
template <int MODE>
__global__ __launch_bounds__(512, 2) void gemm256(
    const unsigned short* __restrict__ A, const unsigned short* __restrict__ B,
    const float* __restrict__ bias, unsigned short* __restrict__ OutH,
    float* __restrict__ OutP)
{
    constexpr int K    = (MODE == 0) ? 1024 : 4096;
    constexpr int NB   = (MODE == 0) ? 4096 : 1024;
    constexpr int KLEN = (MODE == 0) ? 1024 : 2048;
    constexpr int NT   = KLEN / 32;
    constexpr int NWG  = (MODE == 0) ? 512 : 256;
    constexpr int SLOT = 16384;   // ushorts: A 256x32 (8192) + B 256x32 (8192)

    __shared__ __align__(16) unsigned short LDS[3 * SLOT];   // 96 KiB

    int bid = blockIdx.x;
    int swz = (bid & 7) * (NWG / 8) + (bid >> 3);   // XCD-contiguous (NWG%8==0)
    int e, tm, tn, ks;
    if (MODE == 0) {
        e = swz >> 6; int r = swz & 63; tn = r >> 2; tm = r & 3; ks = 0;
    } else {
        e = swz >> 5; int r = swz & 31; ks = r >> 4; int rr = r & 15;
        tn = rr >> 2; tm = rr & 3;
    }
    size_t kOff = (MODE == 0) ? 0 : (size_t)ks * 2048;

    const unsigned short* Ae = A + ((size_t)e * CAP + (size_t)tm * 256) * K + kOff;
    const unsigned short* Be = B + ((size_t)e * NB + (size_t)tn * 256) * K + kOff;

    int tid = threadIdx.x, w = tid >> 6, lane = tid & 63;
    int wm = w >> 2, wn = w & 3;        // wave tile: rows wm*128, cols wn*64
    int fr = lane & 15, kq = lane >> 4;

    // ---- staging: 4 loads/wave/tile (2 A + 2 B), 16 rows per instr ----
    // involution: phys slot s=lane&3 holds logical chunk q=((row>>1)^s)&3;
    // rows base and base+128 share q (128>>1 = 64 ≡ 0 mod 4).
    int lr = lane >> 2;
    int srow = w * 16 + lr;
    int q = (((srow >> 1) ^ lane) & 3);
    const unsigned short* gA = Ae + (size_t)srow * K + q * 8;
    const unsigned short* gB = Be + (size_t)srow * K + q * 8;
    int dA0 = (w * 16) * 32;
    int dA1 = (128 + w * 16) * 32;
    int dB0 = 8192 + (w * 16) * 32;
    int dB1 = 8192 + (128 + w * 16) * 32;

#define STAGE(sl, t_) do { size_t ko_ = (size_t)(t_) * 32;                    \
    gl_lds16(gA + ko_,                    &LDS[(sl) * SLOT + dA0]);           \
    gl_lds16(gA + (size_t)128 * K + ko_,  &LDS[(sl) * SLOT + dA1]);           \
    gl_lds16(gB + ko_,                    &LDS[(sl) * SLOT + dB0]);           \
    gl_lds16(gB + (size_t)128 * K + ko_,  &LDS[(sl) * SLOT + dB1]);           \
} while (0)

    // ---- read offsets: slot ((fr>>1)^kq)&3 (row>>1 ≡ fr>>1 mod 4) ----
    int swc = (((fr >> 1) ^ kq) & 3) << 3;
    int aoff = (wm * 128 + fr) * 32 + swc;          // + mi*512 + slot*SLOT
    int boff = 8192 + (wn * 64 + fr) * 32 + swc;    // + ni*512 + slot*SLOT

    f32x4 acc[8][4];
#pragma unroll
    for (int i = 0; i < 8; i++)
#pragma unroll
        for (int j = 0; j < 4; j++) acc[i][j] = (f32x4){0.f, 0.f, 0.f, 0.f};

    // prologue: stage tiles 0,1; wait tile 0 landed (tile 1 in flight)
    STAGE(0, 0);
    STAGE(1, 1);
    asm volatile("s_waitcnt vmcnt(4)" ::: "memory");
    __builtin_amdgcn_s_barrier();

    int cur = 0, stg = 2;
#pragma unroll 1
    for (int t = 0; t < NT; ++t) {
        if (t + 2 < NT) STAGE(stg, t + 2);

        int sb = cur * SLOT;
        short8 a[8], b[4];
#pragma unroll
        for (int mi = 0; mi < 8; mi++)
            a[mi] = *(const short8*)&LDS[sb + aoff + mi * 512];
#pragma unroll
        for (int ni = 0; ni < 4; ni++)
            b[ni] = *(const short8*)&LDS[sb + boff + ni * 512];
        __builtin_amdgcn_s_setprio(1);
#pragma unroll
        for (int mi = 0; mi < 8; mi++)
#pragma unroll
            for (int ni = 0; ni < 4; ni++)
                acc[mi][ni] = __builtin_amdgcn_mfma_f32_16x16x32_bf16(
                    a[mi], b[ni], acc[mi][ni], 0, 0, 0);
        __builtin_amdgcn_s_setprio(0);

        // tile t+1 landed; tile t+2's 4 loads stay in flight across the barrier
        if (t + 2 < NT)      asm volatile("s_waitcnt vmcnt(4)" ::: "memory");
        else if (t + 1 < NT) asm volatile("s_waitcnt vmcnt(0)" ::: "memory");
        __builtin_amdgcn_s_barrier();
        cur = (cur + 1 == 3) ? 0 : cur + 1;
        stg = (stg + 1 == 3) ? 0 : stg + 1;
    }
#undef STAGE

    if (MODE == 0) {
        // epilogue: two 128-row halves repacked via LDS (64 KB) -> 16B stores
        unsigned short* R = (unsigned short*)LDS;
        float bv[4];
#pragma unroll
        for (int ni = 0; ni < 4; ni++)
            bv[ni] = bias[e * NB + tn * 256 + wn * 64 + ni * 16 + fr];
#pragma unroll 1
        for (int h = 0; h < 2; ++h) {
            __syncthreads();
            if (wm == h) {
#pragma unroll
                for (int mi = 0; mi < 8; mi++) {
#pragma unroll
                    for (int j = 0; j < 4; j++) {
                        int row = mi * 16 + (kq << 2) + j;        // 0..127
#pragma unroll
                        for (int ni = 0; ni < 4; ni++) {
                            int col = wn * 64 + ni * 16 + fr;     // 0..255
                            R[row * 256 + (((col >> 3) ^ (row & 7)) << 3) + (col & 7)] =
                                f2bf(gelu_fast(acc[mi][ni][j] + bv[ni]));
                        }
                    }
                }
            }
            __syncthreads();
            int row = tid >> 2, seg = tid & 3;   // 128 rows x 4 segs of 64 cols
            size_t gb = ((size_t)(e * CAP + tm * 256 + h * 128 + row)) * NB
                        + tn * 256 + seg * 64;
#pragma unroll
            for (int i = 0; i < 8; i++) {
                int chunk = seg * 8 + i;
                *(short8*)&OutH[gb + i * 8] =
                    *(const short8*)&R[row * 256 + ((chunk ^ (row & 7)) << 3)];
            }
        }
    } else {
        // f32 partial store: OutP[ks][e*CAP + r][col] = acc
        float* OP = OutP + (size_t)ks * S_TOK * M_DIM;
#pragma unroll
        for (int mi = 0; mi < 8; mi++) {
#pragma unroll
            for (int j = 0; j < 4; j++) {
                int r = tm * 256 + wm * 128 + mi * 16 + (kq << 2) + j;
                size_t rowbase = ((size_t)(e * CAP + r)) * NB + tn * 256 + wn * 64;
#pragma unroll
                for (int ni = 0; ni < 4; ni++)
                    OP[rowbase + ni * 16 + fr] = acc[mi][ni][j];
            }
        }
    }
}

// ---------------- combine: out[s] = gate[s]*(P0[r]+P1[r]+b2[e]) ----------------
__global__ __launch_bounds__(256) void combine_kernel(
    const float* __restrict__ P, const int* __restrict__ srcmap,
    const float* __restrict__ gate, const float* __restrict__ b2,
    float* __restrict__ out)
{
    int r = blockIdx.x;
    int s = srcmap[r];
    if (s < 0) return;
    int e = r >> 10;
    float g = gate[s];
    int t = threadIdx.x;
    float4 p0 = ((const float4*)P)[r * 256 + t];
    float4 p1 = ((const float4*)(P + (size_t)S_TOK * M_DIM))[r * 256 + t];
    float4 bb = ((const float4*)b2)[e * 256 + t];
    float4 o;
    o.x = g * (p0.x + p1.x + bb.x);
    o.y = g * (p0.y + p1.y + bb.y);
    o.z = g * (p0.z + p1.z + bb.z);
    o.w = g * (p0.w + p1.w + bb.w);
    ((float4*)out)[s * 256 + t] = o;
}

extern "C" void kernel_launch(void* const* d_in, const int* in_sizes, int n_in,
                              void* d_out, int out_size, void* d_ws, size_t ws_size,
                              hipStream_t stream) {
    const float* x  = (const float*)d_in[0];  // [S, M]
    const float* wg = (const float*)d_in[1];  // [M, E]
    const float* w1 = (const float*)d_in[2];  // [E, M, F]
    const float* b1 = (const float*)d_in[3];  // [E, F]
    const float* w2 = (const float*)d_in[4];  // [E, F, M]
    const float* b2 = (const float*)d_in[5];  // [E, M]
    float* out = (float*)d_out;

    char* ws = (char*)d_ws;
    unsigned short* A1  = (unsigned short*)(ws);                       // 16 MiB [E*C][M]
    unsigned short* W1T = (unsigned short*)(ws + (size_t)(16u << 20)); // 64 MiB [E][F][M]
    float*          P   = (float*)(ws + (size_t)(16u << 20));          // 64 MiB overlay (GEMM2 phase)
    unsigned short* W2T = (unsigned short*)(ws + (size_t)(80u << 20)); // 64 MiB [E][M][F]
    unsigned short* H   = (unsigned short*)(ws + (size_t)(144u << 20));// 64 MiB [E][C][F]
    int*   idx  = (int*)(ws + (size_t)(208u << 20));
    float* gate = (float*)(ws + (size_t)(208u << 20) + 32768);
    int*   srcm = (int*)(ws + (size_t)(208u << 20) + 65536);

    hipMemsetAsync(d_out, 0, (size_t)S_TOK * M_DIM * sizeof(float), stream);

    gating_kernel<<<S_TOK / 4, 256, 0, stream>>>(x, wg, idx, gate);
    scan_build<<<1, 1024, 0, stream>>>(idx, srcm);
    dispatch_kernel<<<E_NUM * CAP, 256, 0, stream>>>(x, srcm, A1);
    transpose_cvt<<<dim3(F_DIM / 32, M_DIM / 32, E_NUM), dim3(32, 8), 0, stream>>>(
        w1, W1T, M_DIM, F_DIM);
    transpose_cvt<<<dim3(M_DIM / 32, F_DIM / 32, E_NUM), dim3(32, 8), 0, stream>>>(
        w2, W2T, F_DIM, M_DIM);

    // GEMM1: H = gelu(A1 @ w1 + b1)  256x256 tiles, K=1024; 512 blocks
    gemm256<0><<<512, 512, 0, stream>>>(A1, W1T, b1, H, nullptr);

    // GEMM2: P[ks] = H @ w2 (split-K=2)  256x256 tiles; 256 blocks
    gemm256<1><<<256, 512, 0, stream>>>(H, W2T, nullptr, nullptr, P);

    // combine: out[s] = gate[s]*(P0+P1+b2), scatter via srcmap
    combine_kernel<<<E_NUM * CAP, 256, 0, stream>>>(P, srcm, gate, b2, out);
}

// Round 17
// 331.271 us; speedup vs baseline: 1.2162x; 1.2162x over previous
//
#include <hip/hip_runtime.h>
#include <hip/hip_bf16.h>
#include <math.h>

#define S_TOK 8192
#define M_DIM 1024
#define E_NUM 8
#define F_DIM 4096
#define CAP   1024

typedef short short8 __attribute__((ext_vector_type(8)));
typedef float f32x4 __attribute__((ext_vector_type(4)));
typedef unsigned short ushortx4 __attribute__((ext_vector_type(4)));

__device__ inline unsigned short f2bf(float f) {
    union { float f; unsigned int u; } v; v.f = f;
    unsigned int r = v.u + 0x7fffu + ((v.u >> 16) & 1u);
    return (unsigned short)(r >> 16);
}

__device__ inline float bf2f(unsigned short u) {
    union { unsigned int u; float f; } v; v.u = ((unsigned int)u) << 16;
    return v.f;
}

// gelu(x) = 0.5 x (1 + tanh(y)), y = c(x + 0.044715 x^3) = x*e/(e+1), e=exp(2y)
__device__ inline float gelu_fast(float x) {
    float y = 0.7978845608028654f * (x + 0.044715f * x * x * x);
    if (y > 40.f) return x;
    float e = exp2f(2.8853900817779268f * y);
    return x * e / (e + 1.0f);
}

__device__ inline void gl_lds16(const void* g, void* l) {
    __builtin_amdgcn_global_load_lds(
        (const __attribute__((address_space(1))) unsigned int*)g,
        (__attribute__((address_space(3))) unsigned int*)l, 16, 0, 0);
}

// ---------------- gating ----------------
__global__ __launch_bounds__(256) void gating_kernel(
    const float* __restrict__ x, const float* __restrict__ wg,
    int* __restrict__ idx, float* __restrict__ gate)
{
    int wid = threadIdx.x >> 6;
    int lane = threadIdx.x & 63;
    int s = blockIdx.x * 4 + wid;
    const float* xs = x + (size_t)s * M_DIM;

    double acc[E_NUM];
#pragma unroll
    for (int e = 0; e < E_NUM; e++) acc[e] = 0.0;

    for (int i = lane; i < M_DIM; i += 64) {
        float xv = xs[i];
        float4 wa = *(const float4*)(wg + (size_t)i * E_NUM);
        float4 wb = *(const float4*)(wg + (size_t)i * E_NUM + 4);
        acc[0] += (double)xv * (double)wa.x;
        acc[1] += (double)xv * (double)wa.y;
        acc[2] += (double)xv * (double)wa.z;
        acc[3] += (double)xv * (double)wa.w;
        acc[4] += (double)xv * (double)wb.x;
        acc[5] += (double)xv * (double)wb.y;
        acc[6] += (double)xv * (double)wb.z;
        acc[7] += (double)xv * (double)wb.w;
    }
#pragma unroll
    for (int e = 0; e < E_NUM; e++) {
        double v = acc[e];
        for (int o = 32; o > 0; o >>= 1) v += __shfl_down(v, o, 64);
        acc[e] = v;
    }
    if (lane == 0) {
        double mx = acc[0]; int am = 0;
#pragma unroll
        for (int e = 1; e < E_NUM; e++) {
            if (acc[e] > mx) { mx = acc[e]; am = e; }
        }
        double se = 0.0;
#pragma unroll
        for (int e = 0; e < E_NUM; e++) se += exp(acc[e] - mx);
        idx[s] = am;
        gate[s] = (float)(1.0 / se);
    }
}

// ---------------- scan: token-order slot assignment ----------------
__global__ __launch_bounds__(1024) void scan_build(
    const int* __restrict__ idx, int* __restrict__ srcmap)
{
    __shared__ unsigned int sc[2][4][1024];
    int t = threadIdx.x;

    for (int i = t; i < E_NUM * CAP; i += 1024) srcmap[i] = -1;

    int eid[8];
    unsigned int cnt[E_NUM];
#pragma unroll
    for (int e = 0; e < E_NUM; e++) cnt[e] = 0;
#pragma unroll
    for (int i = 0; i < 8; i++) {
        int e = idx[t * 8 + i];
        eid[i] = e;
        cnt[e]++;
    }
    unsigned int pk[4];
#pragma unroll
    for (int i = 0; i < 4; i++) pk[i] = cnt[2 * i] | (cnt[2 * i + 1] << 16);
#pragma unroll
    for (int i = 0; i < 4; i++) sc[0][i][t] = pk[i];

    int buf = 0;
    for (int ofs = 1; ofs < 1024; ofs <<= 1) {
        __syncthreads();
        unsigned int v[4];
#pragma unroll
        for (int i = 0; i < 4; i++) {
            v[i] = sc[buf][i][t] + ((t >= ofs) ? sc[buf][i][t - ofs] : 0u);
            sc[buf ^ 1][i][t] = v[i];
        }
        buf ^= 1;
    }
    __syncthreads();
    unsigned int pos[E_NUM];
#pragma unroll
    for (int e = 0; e < E_NUM; e++) {
        unsigned int incl = (sc[buf][e >> 1][t] >> ((e & 1) * 16)) & 0xffffu;
        pos[e] = incl - cnt[e];
    }
#pragma unroll
    for (int i = 0; i < 8; i++) {
        int e = eid[i];
        unsigned int p = pos[e]++;
        if (p < CAP) srcmap[e * CAP + p] = t * 8 + i;
    }
}

// ---------------- dispatch: gather rows -> bf16 A1 [E*C][M] ----------------
__global__ __launch_bounds__(256) void dispatch_kernel(
    const float* __restrict__ x, const int* __restrict__ srcmap,
    unsigned short* __restrict__ A1)
{
    int slot = blockIdx.x;
    int s = srcmap[slot];
    int t = threadIdx.x;
    ushortx4 o;
    if (s >= 0) {
        float4 v = ((const float4*)(x + (size_t)s * M_DIM))[t];
        o[0] = f2bf(v.x); o[1] = f2bf(v.y); o[2] = f2bf(v.z); o[3] = f2bf(v.w);
    } else {
        o[0] = 0; o[1] = 0; o[2] = 0; o[3] = 0;
    }
    ((ushortx4*)(A1 + (size_t)slot * M_DIM))[t] = o;
}

// ---------------- transpose + cvt ----------------
__global__ __launch_bounds__(256) void transpose_cvt(
    const float* __restrict__ in, unsigned short* __restrict__ out, int R, int Cc)
{
    __shared__ float tile[32][33];
    int e = blockIdx.z;
    int br = blockIdx.y * 32, bc = blockIdx.x * 32;
    const float* ine = in + (size_t)e * R * Cc;
    unsigned short* oute = out + (size_t)e * R * Cc;
    int tx = threadIdx.x, ty = threadIdx.y;
#pragma unroll
    for (int i = 0; i < 32; i += 8)
        tile[ty + i][tx] = ine[(size_t)(br + ty + i) * Cc + (bc + tx)];
    __syncthreads();
#pragma unroll
    for (int i = 0; i < 32; i += 8)
        oute[(size_t)(bc + ty + i) * R + (br + tx)] = f2bf(tile[tx][ty + i]);
}

// ---------------- 256x128 BK=32 3-slot ring bf16 MFMA GEMM (r11-proven) ----------------
// 8 waves (4M x 2N, per-wave 64x64), 72 KiB LDS ring -> 2 blocks/CU, counted
// vmcnt (3 loads/tile; steady wait vmcnt(3), tile t+2 in flight across barrier).
// MODE 0 (GEMM1): K=1024, NB=4096: OutH = bf16(gelu(acc+bias)), repack stores.
// MODE 1 (GEMM2): split-K=2 (kOff), NB=1024: OutP[ks] = bf16(acc) partials.
template <int MODE>
__global__ __launch_bounds__(512, 4) void gemm256x128(
    const unsigned short* __restrict__ A, const unsigned short* __restrict__ B,
    const float* __restrict__ bias, unsigned short* __restrict__ OutH,
    unsigned short* __restrict__ OutP)
{
    constexpr int K    = (MODE == 0) ? 1024 : 4096;
    constexpr int NB   = (MODE == 0) ? 4096 : 1024;
    constexpr int KLEN = (MODE == 0) ? 1024 : 2048;   // per-block K extent
    constexpr int NT   = KLEN / 32;
    constexpr int NWG  = (MODE == 0) ? 1024 : 512;
    constexpr int SLOT = 12288;   // ushorts per slot: A 256x32 (8192) + B 128x32 (4096)

    __shared__ __align__(16) unsigned short LDS[3 * SLOT];

    int bid = blockIdx.x;
    int swz = (bid & 7) * (NWG / 8) + (bid >> 3);   // XCD-contiguous (NWG%8==0)
    int e, tm, tn, ks;
    if (MODE == 0) {
        e = swz >> 7; int r = swz & 127; tn = r >> 2; tm = r & 3; ks = 0;
    } else {
        e = swz >> 6; int r = swz & 63; ks = r >> 5; int rr = r & 31;
        tn = rr >> 2; tm = rr & 3;
    }
    int kOff = (MODE == 0) ? 0 : ks * 2048;

    const unsigned short* Ae = A + ((size_t)e * CAP + (size_t)tm * 256) * K + kOff;
    const unsigned short* Be = B + ((size_t)e * NB + (size_t)tn * 128) * K + kOff;

    int tid = threadIdx.x, w = tid >> 6, lane = tid & 63;
    int wm = w >> 1, wn = w & 1;            // wave tile: rows wm*64, cols wn*64
    int fr = lane & 15, kq = lane >> 4;
    int r0 = wm * 64, c0 = wn * 64;

    // ---- staging: 3 loads/thread/tile (2 A + 1 B), involution swizzle ----
    // phys chunk slot (lane&3) holds logical chunk (lane&3)^(row&3).
    int lr2 = lane >> 2, sl4 = lane & 3;
    int lc = sl4 ^ (lr2 & 3);
    const unsigned short* gA0 = Ae + (size_t)(w * 16 + lr2) * K + lc * 8;
    const unsigned short* gA1 = Ae + (size_t)(128 + w * 16 + lr2) * K + lc * 8;
    const unsigned short* gB  = Be + (size_t)(w * 16 + lr2) * K + lc * 8;
    int dA0 = (w * 16) * 32;            // + lane*16B by HW
    int dA1 = (128 + w * 16) * 32;
    int dB  = 8192 + (w * 16) * 32;

#define STAGE(sl, t_) do { int ko_ = (t_) * 32;                      \
    gl_lds16(gA0 + ko_, &LDS[(sl) * SLOT + dA0]);                    \
    gl_lds16(gA1 + ko_, &LDS[(sl) * SLOT + dA1]);                    \
    gl_lds16(gB  + ko_, &LDS[(sl) * SLOT + dB]);                     \
} while (0)

    // ---- read offsets (swizzled; row&3 spread over 4 chunk slots) ----
    int swc = ((kq ^ (fr & 3)) << 3);
    int aoff = (r0 + fr) * 32 + swc;          // + mi*512 + slot*SLOT
    int boff = 8192 + (c0 + fr) * 32 + swc;   // + ni*512 + slot*SLOT

    f32x4 acc[4][4];
#pragma unroll
    for (int i = 0; i < 4; i++)
#pragma unroll
        for (int j = 0; j < 4; j++) acc[i][j] = (f32x4){0.f, 0.f, 0.f, 0.f};

    // prologue: stage tiles 0,1; wait tile 0 landed (tile 1 stays in flight)
    STAGE(0, 0);
    STAGE(1, 1);
    asm volatile("s_waitcnt vmcnt(3)" ::: "memory");
    __builtin_amdgcn_s_barrier();

    int cur = 0, stg = 2;
#pragma unroll 1
    for (int t = 0; t < NT; ++t) {
        if (t + 2 < NT) STAGE(stg, t + 2);

        int sb = cur * SLOT;
        short8 a[4], b[4];
#pragma unroll
        for (int mi = 0; mi < 4; mi++)
            a[mi] = *(const short8*)&LDS[sb + aoff + mi * 512];
#pragma unroll
        for (int ni = 0; ni < 4; ni++)
            b[ni] = *(const short8*)&LDS[sb + boff + ni * 512];
        __builtin_amdgcn_s_setprio(1);
#pragma unroll
        for (int mi = 0; mi < 4; mi++)
#pragma unroll
            for (int ni = 0; ni < 4; ni++)
                acc[mi][ni] = __builtin_amdgcn_mfma_f32_16x16x32_bf16(
                    a[mi], b[ni], acc[mi][ni], 0, 0, 0);
        __builtin_amdgcn_s_setprio(0);

        // tile t+1 landed; tile t+2's 3 loads stay in flight across the barrier
        if (t + 2 < NT)      asm volatile("s_waitcnt vmcnt(3)" ::: "memory");
        else if (t + 1 < NT) asm volatile("s_waitcnt vmcnt(0)" ::: "memory");
        __builtin_amdgcn_s_barrier();
        cur = (cur + 1 == 3) ? 0 : cur + 1;
        stg = (stg + 1 == 3) ? 0 : stg + 1;
    }
#undef STAGE

    if (MODE == 0) {
        // swizzled repack (256x128 bf16 = 64KB within 72KB LDS) -> 16B stores
        unsigned short* R = (unsigned short*)LDS;
        float bv[4];
#pragma unroll
        for (int ni = 0; ni < 4; ni++)
            bv[ni] = bias[e * NB + tn * 128 + c0 + ni * 16 + fr];
#pragma unroll
        for (int mi = 0; mi < 4; mi++) {
#pragma unroll
            for (int j = 0; j < 4; j++) {
                int row = wm * 64 + mi * 16 + kq * 4 + j;   // 0..255
#pragma unroll
                for (int ni = 0; ni < 4; ni++) {
                    int col = c0 + ni * 16 + fr;            // 0..127
                    R[row * 128 + (((col >> 3) ^ (row & 7)) << 3) + (col & 7)] =
                        f2bf(gelu_fast(acc[mi][ni][j] + bv[ni]));
                }
            }
        }
        __syncthreads();
        int row = tid >> 1, seg = tid & 1;   // 256 rows x 2 half-rows
        size_t gb = ((size_t)(e * CAP + tm * 256 + row)) * NB + tn * 128 + seg * 64;
#pragma unroll
        for (int i = 0; i < 8; i++) {
            int chunk = seg * 8 + i;
            *(short8*)&OutH[gb + i * 8] =
                *(const short8*)&R[row * 128 + ((chunk ^ (row & 7)) << 3)];
        }
    } else {
        // bf16 partial store: OutP[ks][e*CAP + r][col] = bf16(acc)
        unsigned short* OP = OutP + (size_t)ks * S_TOK * M_DIM;
#pragma unroll
        for (int mi = 0; mi < 4; mi++) {
#pragma unroll
            for (int j = 0; j < 4; j++) {
                int r = tm * 256 + wm * 64 + mi * 16 + kq * 4 + j;
                size_t rowbase = ((size_t)(e * CAP + r)) * NB + tn * 128 + c0;
#pragma unroll
                for (int ni = 0; ni < 4; ni++)
                    OP[rowbase + ni * 16 + fr] = f2bf(acc[mi][ni][j]);
            }
        }
    }
}

// ---------------- combine: out[s] = gate[s]*(P0[r]+P1[r]+b2[e]) ----------------
__global__ __launch_bounds__(256) void combine_kernel(
    const unsigned short* __restrict__ P, const int* __restrict__ srcmap,
    const float* __restrict__ gate, const float* __restrict__ b2,
    float* __restrict__ out)
{
    int r = blockIdx.x;
    int s = srcmap[r];
    if (s < 0) return;
    int e = r >> 10;
    float g = gate[s];
    int t = threadIdx.x;
    ushortx4 p0 = ((const ushortx4*)P)[r * 256 + t];
    ushortx4 p1 = ((const ushortx4*)(P + (size_t)S_TOK * M_DIM))[r * 256 + t];
    float4 bb = ((const float4*)b2)[e * 256 + t];
    float4 o;
    o.x = g * (bf2f(p0[0]) + bf2f(p1[0]) + bb.x);
    o.y = g * (bf2f(p0[1]) + bf2f(p1[1]) + bb.y);
    o.z = g * (bf2f(p0[2]) + bf2f(p1[2]) + bb.z);
    o.w = g * (bf2f(p0[3]) + bf2f(p1[3]) + bb.w);
    ((float4*)out)[s * 256 + t] = o;
}

extern "C" void kernel_launch(void* const* d_in, const int* in_sizes, int n_in,
                              void* d_out, int out_size, void* d_ws, size_t ws_size,
                              hipStream_t stream) {
    const float* x  = (const float*)d_in[0];  // [S, M]
    const float* wg = (const float*)d_in[1];  // [M, E]
    const float* w1 = (const float*)d_in[2];  // [E, M, F]
    const float* b1 = (const float*)d_in[3];  // [E, F]
    const float* w2 = (const float*)d_in[4];  // [E, F, M]
    const float* b2 = (const float*)d_in[5];  // [E, M]
    float* out = (float*)d_out;

    char* ws = (char*)d_ws;
    unsigned short* A1  = (unsigned short*)(ws);                       // 16 MiB [E*C][M]
    unsigned short* W1T = (unsigned short*)(ws + (size_t)(16u << 20)); // 64 MiB [E][F][M]
    unsigned short* P   = (unsigned short*)(ws + (size_t)(16u << 20)); // 32 MiB overlay (GEMM2 phase)
    unsigned short* W2T = (unsigned short*)(ws + (size_t)(80u << 20)); // 64 MiB [E][M][F]
    unsigned short* H   = (unsigned short*)(ws + (size_t)(144u << 20));// 64 MiB [E][C][F]
    int*   idx  = (int*)(ws + (size_t)(208u << 20));
    float* gate = (float*)(ws + (size_t)(208u << 20) + 32768);
    int*   srcm = (int*)(ws + (size_t)(208u << 20) + 65536);

    hipMemsetAsync(d_out, 0, (size_t)S_TOK * M_DIM * sizeof(float), stream);

    gating_kernel<<<S_TOK / 4, 256, 0, stream>>>(x, wg, idx, gate);
    scan_build<<<1, 1024, 0, stream>>>(idx, srcm);
    dispatch_kernel<<<E_NUM * CAP, 256, 0, stream>>>(x, srcm, A1);
    transpose_cvt<<<dim3(F_DIM / 32, M_DIM / 32, E_NUM), dim3(32, 8), 0, stream>>>(
        w1, W1T, M_DIM, F_DIM);
    transpose_cvt<<<dim3(M_DIM / 32, F_DIM / 32, E_NUM), dim3(32, 8), 0, stream>>>(
        w2, W2T, F_DIM, M_DIM);

    // GEMM1: H = gelu(A1 @ w1 + b1)  256x128 tiles, K=1024; 1024 blocks (2/CU)
    gemm256x128<0><<<1024, 512, 0, stream>>>(A1, W1T, b1, H, nullptr);

    // GEMM2: P[ks] = bf16(H @ w2) (split-K=2)  256x128 tiles; 512 blocks (2/CU)
    gemm256x128<1><<<512, 512, 0, stream>>>(H, W2T, nullptr, nullptr, P);

    // combine: out[s] = gate[s]*(P0+P1+b2), scatter via srcmap
    combine_kernel<<<E_NUM * CAP, 256, 0, stream>>>(P, srcm, gate, b2, out);
}